// Round 13
// baseline (79.698 us; speedup 1.0000x reference)
//
#include <hip/hip_runtime.h>
#include <math.h>

typedef float v2 __attribute__((ext_vector_type(2)));

#define SCALE 1073741824.0   // 2^30 fixed-point for deterministic atomic sum
#define NPIX 12582912.0      // 16*3*512*512
#define C1f 1e-4f
#define C2f 9e-4f

struct Wts {
    float w[11];   // V-pass weights
    v2 hp[12];     // H-pass pair weights for element j: (w[j]|0, w[j-1]|0)
};

__device__ __forceinline__ v2 sp(float x) { v2 r; r.x = x; r.y = x; return r; }
__device__ __forceinline__ v2 f2(v2 a, v2 b, v2 c) {
    return __builtin_elementwise_fma(a, b, c);
}

__global__ __launch_bounds__(256, 2) void ssim_main(
    const float* __restrict__ img1, const float* __restrict__ img2,
    unsigned long long* __restrict__ acc, Wts W)
{
    __shared__ float red[4];
    const int tid = threadIdx.x;
    const int lane = tid & 63;
    const int wv = tid >> 6;
    const int r0 = blockIdx.x * 22;            // 24 strips of 22 output rows
    const int plane = blockIdx.y;              // 48 planes
    const int c = wv * 128 + 2 * lane;         // this thread's columns c, c+1

    const float* baseA = img1 + (size_t)plane * 262144;
    const float* baseB = img2 + (size_t)plane * 262144;

    // per-lane clamped chunk offsets (7 x float2 chunks covering [c-6, c+8))
    int off[7];
#pragma unroll
    for (int k = 0; k < 7; ++k) {
        int o = c - 6 + 2 * k;
        off[k] = o < 0 ? 0 : (o > 510 ? 510 : o);
    }
    // per-lane H weight pairs, zeroed where the element column is out of image
    v2 hpl[12];
#pragma unroll
    for (int j = 0; j < 12; ++j) {
        const int col = c - 5 + j;
        hpl[j] = (col >= 0 && col < 512) ? W.hp[j] : sp(0.f);
    }

    v2 rS[11], rD[11], rP[11], rM[11];         // ring: blurred u, v, u^2, v^2
#pragma unroll
    for (int q = 0; q < 11; ++q) {             // zero ring: prologue VOUTs stay
        rS[q] = sp(0.f); rD[q] = sp(0.f);      // finite (den=C1*C2>0), masked
        rP[q] = sp(0.f); rM[q] = sp(0.f);
    }
    v2 a[7], b[7];
    v2 loc = sp(0.f);

    // ---- 33 steps as 3 x one 11-step body (~15 KB: fits 32 KB I$) --------
    // step t=11*it+p: load source row gr=r0-5+t, VOUT output row r0+t-11
    // (masked vm: t>=11 && row<512), push H-blur of row gr (masked m).
    for (int it = 0; it < 3; ++it) {
        const int t0 = 11 * it;
#pragma unroll
        for (int p = 0; p < 11; ++p) {
            const int t = t0 + p;
            const int gr = r0 - 5 + t;
            const int rc = gr < 0 ? 0 : (gr > 511 ? 511 : gr);
            const float* ra = baseA + rc * 512;
            const float* rb = baseB + rc * 512;
#pragma unroll
            for (int k = 0; k < 7; ++k) {      // issue loads first
                a[k] = *(const v2*)(ra + off[k]);
                b[k] = *(const v2*)(rb + off[k]);
            }
            // V-output (ring-only; overlaps the in-flight loads)
            {
                v2 S = sp(0.f), D = sp(0.f), P = sp(0.f), M = sp(0.f);
#pragma unroll
                for (int k = 0; k < 11; ++k) {
                    const int q = (p + k) % 11; // constant after unroll
                    const v2 wk = sp(W.w[k]);
                    S = f2(wk, rS[q], S);
                    D = f2(wk, rD[q], D);
                    P = f2(wk, rP[q], P);
                    M = f2(wk, rM[q], M);
                }
                const v2 ss = S * S, dd = D * D;
                const v2 mu12  = (ss - dd) * sp(0.25f);
                const v2 musq  = (ss + dd) * sp(0.5f);
                const v2 sig12 = (P - M) * sp(0.25f) - mu12;
                const v2 sigsm = (P + M) * sp(0.5f) - musq;
                const v2 num = (sp(2.f) * mu12 + sp(C1f)) *
                               (sp(2.f) * sig12 + sp(C2f));
                const v2 den = (musq + sp(C1f)) * (sigsm + sp(C2f));
                v2 r;
                r.x = __builtin_amdgcn_rcpf(den.x);
                r.y = __builtin_amdgcn_rcpf(den.y);
                r = r * (sp(2.f) - den * r);   // one NR step
                const float vm =
                    (t >= 11 && (r0 + t - 11) < 512) ? 1.f : 0.f;
                loc = f2(num * sp(vm), r, loc);
            }
            // H-push row gr into ring slot p
            {
                v2 hS = sp(0.f), hD = sp(0.f), hP = sp(0.f), hM = sp(0.f);
#pragma unroll
                for (int j = 0; j < 12; ++j) {
                    const int e = j + 1;       // element col = c - 6 + e
                    const float xa = (e & 1) ? a[e >> 1].y : a[e >> 1].x;
                    const float xb = (e & 1) ? b[e >> 1].y : b[e >> 1].x;
                    const float u = xa + xb, v = xa - xb;
                    hS = f2(hpl[j], sp(u), hS);
                    hD = f2(hpl[j], sp(v), hD);
                    hP = f2(hpl[j], sp(u * u), hP);
                    hM = f2(hpl[j], sp(v * v), hM);
                }
                const float m = ((unsigned)gr < 512u) ? 1.f : 0.f;
                const v2 mm = sp(m);
                rS[p] = hS * mm; rD[p] = hD * mm;
                rP[p] = hP * mm; rM[p] = hM * mm;
            }
            __builtin_amdgcn_sched_barrier(0); // fence: bounds live ranges
        }
    }

    // ---- reduction -> fixed-point global atomic ----
    float l = loc.x + loc.y;
#pragma unroll
    for (int o2 = 32; o2; o2 >>= 1)
        l += __shfl_down(l, o2, 64);
    if (lane == 0) red[wv] = l;
    __syncthreads();
    if (tid == 0) {
        const float bs = red[0] + red[1] + red[2] + red[3];
        const unsigned long long q =
            (unsigned long long)__double2ll_rn((double)bs * SCALE);
        atomicAdd(acc, q);
    }
}

__global__ void ssim_final(const unsigned long long* __restrict__ acc,
                           float* __restrict__ out)
{
    if (threadIdx.x == 0)
        out[0] = (float)((double)(*acc) * (1.0 / SCALE) / NPIX);
}

extern "C" void kernel_launch(void* const* d_in, const int* in_sizes, int n_in,
                              void* d_out, int out_size, void* d_ws, size_t ws_size,
                              hipStream_t stream) {
    const float* img1 = (const float*)d_in[0];
    const float* img2 = (const float*)d_in[1];
    float* out = (float*)d_out;
    unsigned long long* acc = (unsigned long long*)d_ws;

    double g[11], ssum = 0.0;
    for (int i = 0; i < 11; ++i) {
        const double d = (double)(i - 5);
        g[i] = exp(-(d * d) / 4.5);
        ssum += g[i];
    }
    Wts W;
    for (int i = 0; i < 11; ++i) W.w[i] = (float)(g[i] / ssum);
    for (int j = 0; j < 12; ++j) {
        v2 p;
        p.x = (j <= 10) ? W.w[j] : 0.f;      // out0 weight for window col c-5+j
        p.y = (j >= 1) ? W.w[j - 1] : 0.f;   // out1 weight
        W.hp[j] = p;
    }

    hipMemsetAsync(d_ws, 0, sizeof(unsigned long long), stream);
    ssim_main<<<dim3(24, 48), 256, 0, stream>>>(img1, img2, acc, W);
    ssim_final<<<1, 64, 0, stream>>>(acc, out);
}